// Round 1
// 851.230 us; speedup vs baseline: 1.0901x; 1.0901x over previous
//
#include <hip/hip_runtime.h>
#include <math.h>

#define NN 100000
#define NE 1000000
#define D 64
#define L 3
#define RVQ 3
#define CODES 16
#define BN_EPS 1e-5f
#define COMMIT_W 0.25f

#define GRID_A 2048   // blocks for matvec kernels (fixed: partials + node mapping)

// ---------------- ws layout (in 4-byte units) ----------------
#define OFS_ROWPTR 0           // 100001 ints
#define OFS_CNT    100016      // 100000 ints
#define OFS_CURSOR 200032      // 100000 ints
#define OFS_BSUMS  300048      // 128 ints
#define OFS_BOFFS  300176      // 128 ints
#define OFS_STATS  300304      // 3*128 floats (sum[64],sumsq[64] per layer)
#define OFS_CSR    300800      // 1000000 ints
#define OFS_HA     1300800     // 6400000 floats
#define OFS_HB     7700800     // 6400000 floats
#define OFS_XLOC   14100800    // 6400000 floats
#define OFS_PART   20500800    // 2048*128 floats = 262144
// total = 20,762,944 * 4 B ~= 83 MB

// ---------------- d_out layout (floats) ----------------
#define OUT_PRED   0
#define OUT_COMMIT (NN * D)                       // 6,400,000
#define OUT_IDS    (NN * D + 1)                   // 6,400,001
#define OUT_GNN    (NN * D + 1 + NN * (L * RVQ))  // 7,300,001

static __device__ __forceinline__ float waveSum(float v) {
    #pragma unroll
    for (int off = 32; off; off >>= 1) v += __shfl_xor(v, off, 64);
    return v;
}

// DPP quad-permute helpers: value from lane^1 / lane^2 within each quad.
// quad_perm(1,0,3,2) = 0xB1 ; quad_perm(2,3,0,1) = 0x4E. VALU-only (no DS pipe).
static __device__ __forceinline__ float qxor1(float v) {
    return __int_as_float(__builtin_amdgcn_mov_dpp(__float_as_int(v), 0xB1, 0xF, 0xF, 1));
}
static __device__ __forceinline__ float qxor2(float v) {
    return __int_as_float(__builtin_amdgcn_mov_dpp(__float_as_int(v), 0x4E, 0xF, 0xF, 1));
}

// ---------------- CSR build ----------------
__global__ void k_count(const int* __restrict__ dst, int* __restrict__ cnt) {
    int e = blockIdx.x * blockDim.x + threadIdx.x;
    if (e < NE) atomicAdd(&cnt[dst[e]], 1);
}

#define SCAN_B 1024
__global__ void k_scan1(const int* __restrict__ cnt, int* __restrict__ rowptr,
                        int* __restrict__ bsums) {
    __shared__ int sm[SCAN_B];
    int t = threadIdx.x;
    int i = blockIdx.x * SCAN_B + t;
    int v = (i < NN) ? cnt[i] : 0;
    sm[t] = v;
    __syncthreads();
    for (int off = 1; off < SCAN_B; off <<= 1) {
        int add = (t >= off) ? sm[t - off] : 0;
        __syncthreads();
        sm[t] += add;
        __syncthreads();
    }
    if (i < NN) rowptr[i + 1] = sm[t];
    if (t == SCAN_B - 1) bsums[blockIdx.x] = sm[t];
}

__global__ void k_scan2(const int* __restrict__ bsums, int* __restrict__ boffs, int nb) {
    __shared__ int sm[SCAN_B];
    int t = threadIdx.x;
    int orig = (t < nb) ? bsums[t] : 0;
    sm[t] = orig;
    __syncthreads();
    for (int off = 1; off < SCAN_B; off <<= 1) {
        int add = (t >= off) ? sm[t - off] : 0;
        __syncthreads();
        sm[t] += add;
        __syncthreads();
    }
    if (t < nb) boffs[t] = sm[t] - orig;  // exclusive
}

__global__ void k_scan3(int* __restrict__ rowptr, const int* __restrict__ boffs) {
    int i = blockIdx.x * SCAN_B + threadIdx.x;
    if (i < NN) rowptr[i + 1] += boffs[blockIdx.x];
    if (i == 0) rowptr[0] = 0;
}

__global__ void k_cursor(const int* __restrict__ rowptr, int* __restrict__ cursor) {
    int i = blockIdx.x * blockDim.x + threadIdx.x;
    if (i < NN) cursor[i] = rowptr[i];
}

__global__ void k_fill(const int* __restrict__ src, const int* __restrict__ dst,
                       int* __restrict__ cursor, int* __restrict__ csr_src) {
    int e = blockIdx.x * blockDim.x + threadIdx.x;
    if (e < NE) {
        int p = atomicAdd(&cursor[dst[e]], 1);
        csr_src[p] = src[e];
    }
}

// Canonicalize row order so the neighbor-sum order is deterministic.
__global__ void k_sortrows(const int* __restrict__ rowptr, int* __restrict__ csr) {
    int n = blockIdx.x * blockDim.x + threadIdx.x;
    if (n >= NN) return;
    int r0 = rowptr[n], r1 = rowptr[n + 1];
    for (int i = r0 + 1; i < r1; ++i) {
        int v = csr[i];
        int j = i - 1;
        while (j >= r0 && csr[j] > v) { csr[j + 1] = csr[j]; --j; }
        csr[j + 1] = v;
    }
}

// ---------------- Gather: mean of neighbor rows -> mean_out ----------------
__global__ __launch_bounds__(256) void k_gather(
    const float* __restrict__ h, const int* __restrict__ rowptr,
    const int* __restrict__ csr_src, float* __restrict__ mean_out) {
    int t = threadIdx.x;
    int lane = t & 63, wid = t >> 6;
    int n = blockIdx.x * 4 + wid;
    if (n >= NN) return;

    int r0 = rowptr[n], r1 = rowptr[n + 1];
    float s = 0.f;
    for (int base = r0; base < r1; base += 64) {
        int last = r1 - 1;
        int ii = base + lane;
        int idx = csr_src[(ii <= last) ? ii : last];  // coalesced, clamped
        int m = r1 - base;
        if (m > 64) m = 64;
        int j = 0;
        for (; j + 8 <= m; j += 8) {
            int i0 = __shfl(idx, j + 0, 64), i1 = __shfl(idx, j + 1, 64);
            int i2 = __shfl(idx, j + 2, 64), i3 = __shfl(idx, j + 3, 64);
            int i4 = __shfl(idx, j + 4, 64), i5 = __shfl(idx, j + 5, 64);
            int i6 = __shfl(idx, j + 6, 64), i7 = __shfl(idx, j + 7, 64);
            float v0 = h[i0 * D + lane], v1 = h[i1 * D + lane];
            float v2 = h[i2 * D + lane], v3 = h[i3 * D + lane];
            float v4 = h[i4 * D + lane], v5 = h[i5 * D + lane];
            float v6 = h[i6 * D + lane], v7 = h[i7 * D + lane];
            s += v0; s += v1; s += v2; s += v3;
            s += v4; s += v5; s += v6; s += v7;
        }
        for (; j + 4 <= m; j += 4) {
            int i0 = __shfl(idx, j + 0, 64), i1 = __shfl(idx, j + 1, 64);
            int i2 = __shfl(idx, j + 2, 64), i3 = __shfl(idx, j + 3, 64);
            float v0 = h[i0 * D + lane], v1 = h[i1 * D + lane];
            float v2 = h[i2 * D + lane], v3 = h[i3 * D + lane];
            s += v0; s += v1; s += v2; s += v3;
        }
        for (; j < m; ++j) {
            int i0 = __shfl(idx, j, 64);
            s += h[i0 * D + lane];
        }
    }
    float deg = (float)(r1 - r0);
    mean_out[n * D + lane] = s / fmaxf(deg, 1.0f);
}

// ---------------- Matvec: SAGE transform + skip linear + BN stat partials --
__global__ __launch_bounds__(256) void k_matvec(
    const float* __restrict__ h, float* __restrict__ hp,
    const float* __restrict__ Wa, const float* __restrict__ ba,
    const float* __restrict__ Wr, const float* __restrict__ Wl,
    const float* __restrict__ bl, float* __restrict__ partials) {
    __shared__ float red[2][4][D];
    __shared__ float lbuf[4][2][128];   // [wave][parity][mean(64) | h(64)]
    int t = threadIdx.x, lane = t & 63, wid = t >> 6;

    float wa[D], wr[D], wl[D];
    #pragma unroll
    for (int k = 0; k < D; ++k) {
        wa[k] = Wa[k * D + lane];
        wr[k] = Wr[k * D + lane];
        wl[k] = Wl[k * D + lane];
    }
    float bav = ba[lane], blv = bl[lane];

    int wg = blockIdx.x * 4 + wid;
    const int wstep = GRID_A * 4;
    float accS = 0.f, accQ = 0.f;

    int seg = lane >> 4;   // 0: stage mean row, 1: stage h row, 2/3: idle
    int sl  = lane & 15;

    // preload first node into parity 0 (every wave has >=1 node: wg < 8192)
    {
        float4 v = {0.f, 0.f, 0.f, 0.f};
        if (seg == 0)      v = *(const float4*)(hp + (size_t)wg * D + 4 * sl);
        else if (seg == 1) v = *(const float4*)(h  + (size_t)wg * D + 4 * sl);
        if (seg < 2) *(float4*)&lbuf[wid][0][seg * 64 + 4 * sl] = v;
    }

    int p = 0;
    for (int n = wg; n < NN; n += wstep) {
        int nn = n + wstep;
        bool havepf = (nn < NN);
        float4 pf = {0.f, 0.f, 0.f, 0.f};
        if (havepf && seg < 2) {
            const float* srcp = (seg == 0) ? hp : h;
            pf = *(const float4*)(srcp + (size_t)nn * D + 4 * sl);
        }

        const float* mb = &lbuf[wid][p][0];
        const float* hb = &lbuf[wid][p][64];
        float a = 0.f, r = 0.f, lv = 0.f;
        #pragma unroll
        for (int j = 0; j < 16; ++j) {
            float4 m4 = *(const float4*)(mb + 4 * j);   // broadcast ds_read_b128
            float4 h4 = *(const float4*)(hb + 4 * j);
            a += m4.x * wa[4 * j + 0]; r += h4.x * wr[4 * j + 0]; lv += h4.x * wl[4 * j + 0];
            a += m4.y * wa[4 * j + 1]; r += h4.y * wr[4 * j + 1]; lv += h4.y * wl[4 * j + 1];
            a += m4.z * wa[4 * j + 2]; r += h4.z * wr[4 * j + 2]; lv += h4.z * wl[4 * j + 2];
            a += m4.w * wa[4 * j + 3]; r += h4.w * wr[4 * j + 3]; lv += h4.w * wl[4 * j + 3];
        }
        float sage = a + bav + r;
        float ss = waveSum(sage * sage);
        float inv = 1.0f / (sqrtf(ss) + 1e-12f);
        float hpv = sage * inv + lv + blv;
        hp[(size_t)n * D + lane] = hpv;
        accS += hpv;
        accQ += hpv * hpv;

        if (havepf && seg < 2)
            *(float4*)&lbuf[wid][p ^ 1][seg * 64 + 4 * sl] = pf;
        p ^= 1;
    }

    red[0][wid][lane] = accS;
    red[1][wid][lane] = accQ;
    __syncthreads();
    if (wid == 0) {
        float s0 = (red[0][0][lane] + red[0][1][lane]) + (red[0][2][lane] + red[0][3][lane]);
        float q0 = (red[1][0][lane] + red[1][1][lane]) + (red[1][2][lane] + red[1][3][lane]);
        partials[blockIdx.x * 128 + lane]      = s0;
        partials[blockIdx.x * 128 + 64 + lane] = q0;
    }
}

// Parallel deterministic reduction of BN stat partials.
__global__ __launch_bounds__(256) void k_red_stats(
    const float* __restrict__ part, float* __restrict__ stats) {
    __shared__ float sm[256];
    int c = blockIdx.x;      // 0..127
    int i = threadIdx.x;     // 0..255
    float s = 0.f;
    #pragma unroll
    for (int k = 0; k < 8; ++k)
        s += part[(size_t)(i * 8 + k) * 128 + c];
    sm[i] = s;
    __syncthreads();
    #pragma unroll
    for (int off = 128; off >= 1; off >>= 1) {
        if (i < off) sm[i] += sm[i + off];
        __syncthreads();
    }
    if (i == 0) stats[c] = sm[0];
}

// ---------------- Layer part B: BN + ReLU + x_local accumulate + residual VQ
// Quad-per-node rewrite: 4 lanes own one node (16 channels each). Residual
// lives in registers (res[16]); the per-level LDS write/re-gather round trip
// and all 10 ds_bpermute reduce/argmax ops of the old wave-per-node scheme
// are gone. Quarter sums use DPP quad_perm (VALU pipe); the pairwise tree
// (p0+p1)+(p2+p3) over identical 16-channel groups is bit-identical to the
// old shfl_xor(16)/(32) reduction, and the serial strict-> argmax scan equals
// the old min-index-on-ties butterfly. Codebook is broadcast-read from LDS
// (CBSTRIDE=68 keeps float4 alignment; broadcast/2-way banking is free).
#define CBSTRIDE 68
__global__ __launch_bounds__(256) void k_layer_b(
    float* __restrict__ hp,              // in: pre-BN h'; out: post-ReLU h
    const float* __restrict__ stats,
    const float* __restrict__ gamma, const float* __restrict__ beta,
    const float* __restrict__ cbs,       // [RVQ][CODES][D] for this layer
    float* __restrict__ x_local,
    float* __restrict__ ids_out,         // [NN][L*RVQ] region base
    int layer, float* __restrict__ commit, int first_layer) {
    __shared__ alignas(16) float scb[RVQ * CODES * CBSTRIDE];
    __shared__ alignas(16) float sscale[D];
    __shared__ alignas(16) float sshift[D];
    __shared__ float sred[4];
    int t = threadIdx.x, lane = t & 63, wid = t >> 6;

    // normalize codebook rows into LDS (identical math to before)
    for (int row = wid; row < RVQ * CODES; row += 4) {
        float v = cbs[row * D + lane];
        float ss = waveSum(v * v);
        scb[row * CBSTRIDE + lane] = v / (sqrtf(ss) + 1e-12f);
    }
    // BN scale/shift per channel
    if (t < D) {
        float mu = stats[t] * (1.0f / NN);
        float var = stats[64 + t] * (1.0f / NN) - mu * mu;
        float scale = rsqrtf(var + BN_EPS) * gamma[t];
        sscale[t] = scale;
        sshift[t] = beta[t] - mu * scale;
    }
    __syncthreads();

    int gid = blockIdx.x * 256 + t;
    int node = gid >> 2;      // one node per quad of lanes
    int part = t & 3;         // which 16-channel slice this lane owns
    float closs = 0.f;

    if (node < NN) {
        float res[16];
        size_t base = (size_t)node * D + part * 16;
        const float4* hr = (const float4*)(hp + base);
        float4* hw = (float4*)(hp + base);
        float4* xw = (float4*)(x_local + base);
        const float4* scp = (const float4*)(sscale + part * 16);
        const float4* shp = (const float4*)(sshift + part * 16);

        // BN + ReLU + hp store + x_local accumulate, residual into registers
        #pragma unroll
        for (int i = 0; i < 4; ++i) {
            float4 v = hr[i];
            float4 sc = scp[i], sh = shp[i];
            float4 hn;
            hn.x = fmaxf(v.x * sc.x + sh.x, 0.f);
            hn.y = fmaxf(v.y * sc.y + sh.y, 0.f);
            hn.z = fmaxf(v.z * sc.z + sh.z, 0.f);
            hn.w = fmaxf(v.w * sc.w + sh.w, 0.f);
            hw[i] = hn;
            if (first_layer) {
                xw[i] = hn;
            } else {
                float4 xl = xw[i];
                xl.x += hn.x; xl.y += hn.y; xl.z += hn.z; xl.w += hn.w;
                xw[i] = xl;
            }
            res[4 * i + 0] = hn.x; res[4 * i + 1] = hn.y;
            res[4 * i + 2] = hn.z; res[4 * i + 3] = hn.w;
        }

        int bis[RVQ];
        #pragma unroll
        for (int r = 0; r < RVQ; ++r) {
            float sims[CODES];
            #pragma unroll
            for (int j = 0; j < CODES; ++j) {
                const float* cr = &scb[(r * CODES + j) * CBSTRIDE + part * 16];
                float4 c0 = *(const float4*)(cr + 0);
                float4 c1 = *(const float4*)(cr + 4);
                float4 c2 = *(const float4*)(cr + 8);
                float4 c3 = *(const float4*)(cr + 12);
                // serial partial over this lane's 16 channels (same order as before)
                float a = res[0] * c0.x;
                a += res[1] * c0.y;  a += res[2] * c0.z;  a += res[3] * c0.w;
                a += res[4] * c1.x;  a += res[5] * c1.y;  a += res[6] * c1.z;  a += res[7] * c1.w;
                a += res[8] * c2.x;  a += res[9] * c2.y;  a += res[10] * c2.z; a += res[11] * c2.w;
                a += res[12] * c3.x; a += res[13] * c3.y; a += res[14] * c3.z; a += res[15] * c3.w;
                // quad reduce: (p0+p1)+(p2+p3) — bit-identical to old xor16/xor32 tree
                float b = a + qxor1(a);
                sims[j] = b + qxor2(b);
            }
            // first-max scan (== old min-index-on-ties butterfly)
            float bv = sims[0];
            int bi = 0;
            #pragma unroll
            for (int j = 1; j < CODES; ++j)
                if (sims[j] > bv) { bv = sims[j]; bi = j; }

            const float* qr = &scb[(r * CODES + bi) * CBSTRIDE + part * 16];
            #pragma unroll
            for (int i = 0; i < 4; ++i) {
                float4 q = *(const float4*)(qr + 4 * i);
                float d0 = q.x - res[4 * i + 0]; closs += d0 * d0; res[4 * i + 0] = -d0;
                float d1 = q.y - res[4 * i + 1]; closs += d1 * d1; res[4 * i + 1] = -d1;
                float d2 = q.z - res[4 * i + 2]; closs += d2 * d2; res[4 * i + 2] = -d2;
                float d3 = q.w - res[4 * i + 3]; closs += d3 * d3; res[4 * i + 3] = -d3;
            }
            bis[r] = bi;
        }
        if (part == 0) {
            ids_out[(size_t)node * (L * RVQ) + layer * RVQ + 0] = (float)bis[0];
            ids_out[(size_t)node * (L * RVQ) + layer * RVQ + 1] = (float)bis[1];
            ids_out[(size_t)node * (L * RVQ) + layer * RVQ + 2] = (float)bis[2];
        }
    }

    closs = waveSum(closs);
    if (lane == 0) sred[wid] = closs;
    __syncthreads();
    if (t == 0) {
        float tot = (sred[0] + sred[1]) + (sred[2] + sred[3]);
        atomicAdd(commit, tot * (COMMIT_W / (float)(NN * D)));
    }
}

// ---------------- Heads ----------------
__global__ __launch_bounds__(256, 2) void k_head(
    const float* __restrict__ x_local,
    const float* __restrict__ Wp, const float* __restrict__ bp,
    const float* __restrict__ Wg, const float* __restrict__ bg,
    float* __restrict__ pred, float* __restrict__ gnn) {
    int t = threadIdx.x, lane = t & 63, wid = t >> 6;
    int jsafe = (lane < 9) ? lane : 0;

    float wp[D], wg[D];
    #pragma unroll
    for (int k = 0; k < D; ++k) {
        wp[k] = Wp[k * D + lane];
        wg[k] = Wg[k * 9 + jsafe];
    }
    float bpv = bp[lane], bgv = bg[jsafe];

    int w = blockIdx.x * 4 + wid;
    int wstep = gridDim.x * 4;
    for (int n = w; n < NN; n += wstep) {
        int nu = __builtin_amdgcn_readfirstlane(n);
        const float4* xrow = (const float4*)(x_local + (size_t)nu * D);
        float p = 0.f, g = 0.f;
        #pragma unroll
        for (int j = 0; j < 16; ++j) {
            float4 x4 = xrow[j];
            p += x4.x * wp[4 * j + 0]; g += x4.x * wg[4 * j + 0];
            p += x4.y * wp[4 * j + 1]; g += x4.y * wg[4 * j + 1];
            p += x4.z * wp[4 * j + 2]; g += x4.z * wg[4 * j + 2];
            p += x4.w * wp[4 * j + 3]; g += x4.w * wg[4 * j + 3];
        }
        pred[(size_t)n * D + lane] = p + bpv;
        if (lane < 9) gnn[(size_t)n * 9 + lane] = g + bgv;
    }
}

extern "C" void kernel_launch(void* const* d_in, const int* in_sizes, int n_in,
                              void* d_out, int out_size, void* d_ws, size_t ws_size,
                              hipStream_t stream) {
    const float* x   = (const float*)d_in[0];
    const int* ei    = (const int*)d_in[1];
    const float* Wa  = (const float*)d_in[2];
    const float* ba  = (const float*)d_in[3];
    const float* Wr  = (const float*)d_in[4];
    const float* Wl  = (const float*)d_in[5];
    const float* bl  = (const float*)d_in[6];
    const float* gamma = (const float*)d_in[7];
    const float* beta  = (const float*)d_in[8];
    const float* cbs = (const float*)d_in[9];
    const float* Wp  = (const float*)d_in[10];
    const float* bp  = (const float*)d_in[11];
    const float* Wg  = (const float*)d_in[12];
    const float* bg  = (const float*)d_in[13];

    const int* src = ei;
    const int* dst = ei + NE;

    int*   ws_i  = (int*)d_ws;
    float* ws_f  = (float*)d_ws;
    int* rowptr  = ws_i + OFS_ROWPTR;
    int* cnt     = ws_i + OFS_CNT;
    int* cursor  = ws_i + OFS_CURSOR;
    int* bsums   = ws_i + OFS_BSUMS;
    int* boffs   = ws_i + OFS_BOFFS;
    float* stats = ws_f + OFS_STATS;
    int* csr_src = ws_i + OFS_CSR;
    float* hA    = ws_f + OFS_HA;
    float* hB    = ws_f + OFS_HB;
    float* xloc  = ws_f + OFS_XLOC;
    float* part  = ws_f + OFS_PART;

    float* out    = (float*)d_out;
    float* pred   = out + OUT_PRED;
    float* commit = out + OUT_COMMIT;
    float* ids    = out + OUT_IDS;
    float* gnn    = out + OUT_GNN;

    hipMemsetAsync(cnt, 0, NN * sizeof(int), stream);
    hipMemsetAsync(commit, 0, sizeof(float), stream);

    // CSR build
    k_count<<<(NE + 255) / 256, 256, 0, stream>>>(dst, cnt);
    int nscan = (NN + SCAN_B - 1) / SCAN_B;  // 98
    k_scan1<<<nscan, SCAN_B, 0, stream>>>(cnt, rowptr, bsums);
    k_scan2<<<1, SCAN_B, 0, stream>>>(bsums, boffs, nscan);
    k_scan3<<<nscan, SCAN_B, 0, stream>>>(rowptr, boffs);
    k_cursor<<<(NN + 1023) / 1024, 1024, 0, stream>>>(rowptr, cursor);
    k_fill<<<(NE + 255) / 256, 256, 0, stream>>>(src, dst, cursor, csr_src);
    k_sortrows<<<(NN + 255) / 256, 256, 0, stream>>>(rowptr, csr_src);

    // layers
    const float* hin = x;
    float* bufs[2] = {hA, hB};
    const int nblk_b = (NN * 4 + 255) / 256;  // 1563 blocks, one node per quad
    for (int i = 0; i < L; ++i) {
        float* hp = bufs[i & 1];
        k_gather<<<(NN + 3) / 4, 256, 0, stream>>>(hin, rowptr, csr_src, hp);
        k_matvec<<<GRID_A, 256, 0, stream>>>(hin, hp,
                                             Wa + i * D * D, ba + i * D,
                                             Wr + i * D * D, Wl + i * D * D, bl + i * D,
                                             part);
        k_red_stats<<<128, 256, 0, stream>>>(part, stats + i * 128);
        k_layer_b<<<nblk_b, 256, 0, stream>>>(hp, stats + i * 128,
                                              gamma + i * D, beta + i * D,
                                              cbs + i * RVQ * CODES * D,
                                              xloc, ids, i, commit, (i == 0) ? 1 : 0);
        hin = hp;
    }

    // heads
    k_head<<<2048, 256, 0, stream>>>(xloc, Wp, bp, Wg, bg, pred, gnn);
}

// Round 2
// 843.063 us; speedup vs baseline: 1.1007x; 1.0097x over previous
//
#include <hip/hip_runtime.h>
#include <math.h>

#define NN 100000
#define NE 1000000
#define D 64
#define L 3
#define RVQ 3
#define CODES 16
#define BN_EPS 1e-5f
#define COMMIT_W 0.25f

#define GRID_A 2048   // blocks for bnstats kernel (fixed: partials + node mapping)

// ---------------- ws layout (in 4-byte units) ----------------
#define OFS_ROWPTR 0           // 100001 ints
#define OFS_CNT    100016      // 100000 ints
#define OFS_CURSOR 200032      // 100000 ints
#define OFS_BSUMS  300048      // 128 ints
#define OFS_BOFFS  300176      // 128 ints
#define OFS_STATS  300304      // 3*128 floats (sum[64],sumsq[64] per layer)
#define OFS_CSR    300800      // 1000000 ints
#define OFS_HA     1300800     // 6400000 floats
#define OFS_HB     7700800     // 6400000 floats
#define OFS_XLOC   14100800    // 6400000 floats
#define OFS_PART   20500800    // 2048*128 floats = 262144
// total = 20,762,944 * 4 B ~= 83 MB

// ---------------- d_out layout (floats) ----------------
#define OUT_PRED   0
#define OUT_COMMIT (NN * D)                       // 6,400,000
#define OUT_IDS    (NN * D + 1)                   // 6,400,001
#define OUT_GNN    (NN * D + 1 + NN * (L * RVQ))  // 7,300,001

static __device__ __forceinline__ float waveSum(float v) {
    #pragma unroll
    for (int off = 32; off; off >>= 1) v += __shfl_xor(v, off, 64);
    return v;
}

// DPP quad-permute helpers: value from lane^1 / lane^2 within each quad.
static __device__ __forceinline__ float qxor1(float v) {
    return __int_as_float(__builtin_amdgcn_mov_dpp(__float_as_int(v), 0xB1, 0xF, 0xF, 1));
}
static __device__ __forceinline__ float qxor2(float v) {
    return __int_as_float(__builtin_amdgcn_mov_dpp(__float_as_int(v), 0x4E, 0xF, 0xF, 1));
}

// compile-time-lane broadcast (SGPR result, feeds v_fmac as scalar operand)
#define RLF(v, li) __int_as_float(__builtin_amdgcn_readlane(__float_as_int(v), (li)))

// ---------------- CSR build ----------------
__global__ void k_count(const int* __restrict__ dst, int* __restrict__ cnt) {
    int e = blockIdx.x * blockDim.x + threadIdx.x;
    if (e < NE) atomicAdd(&cnt[dst[e]], 1);
}

#define SCAN_B 1024
__global__ void k_scan1(const int* __restrict__ cnt, int* __restrict__ rowptr,
                        int* __restrict__ bsums) {
    __shared__ int sm[SCAN_B];
    int t = threadIdx.x;
    int i = blockIdx.x * SCAN_B + t;
    int v = (i < NN) ? cnt[i] : 0;
    sm[t] = v;
    __syncthreads();
    for (int off = 1; off < SCAN_B; off <<= 1) {
        int add = (t >= off) ? sm[t - off] : 0;
        __syncthreads();
        sm[t] += add;
        __syncthreads();
    }
    if (i < NN) rowptr[i + 1] = sm[t];
    if (t == SCAN_B - 1) bsums[blockIdx.x] = sm[t];
}

__global__ void k_scan2(const int* __restrict__ bsums, int* __restrict__ boffs, int nb) {
    __shared__ int sm[SCAN_B];
    int t = threadIdx.x;
    int orig = (t < nb) ? bsums[t] : 0;
    sm[t] = orig;
    __syncthreads();
    for (int off = 1; off < SCAN_B; off <<= 1) {
        int add = (t >= off) ? sm[t - off] : 0;
        __syncthreads();
        sm[t] += add;
        __syncthreads();
    }
    if (t < nb) boffs[t] = sm[t] - orig;  // exclusive
}

__global__ void k_scan3(int* __restrict__ rowptr, const int* __restrict__ boffs) {
    int i = blockIdx.x * SCAN_B + threadIdx.x;
    if (i < NN) rowptr[i + 1] += boffs[blockIdx.x];
    if (i == 0) rowptr[0] = 0;
}

__global__ void k_cursor(const int* __restrict__ rowptr, int* __restrict__ cursor) {
    int i = blockIdx.x * blockDim.x + threadIdx.x;
    if (i < NN) cursor[i] = rowptr[i];
}

__global__ void k_fill(const int* __restrict__ src, const int* __restrict__ dst,
                       int* __restrict__ cursor, int* __restrict__ csr_src) {
    int e = blockIdx.x * blockDim.x + threadIdx.x;
    if (e < NE) {
        int p = atomicAdd(&cursor[dst[e]], 1);
        csr_src[p] = src[e];
    }
}

// Canonicalize row order so the neighbor-sum order is deterministic.
__global__ void k_sortrows(const int* __restrict__ rowptr, int* __restrict__ csr) {
    int n = blockIdx.x * blockDim.x + threadIdx.x;
    if (n >= NN) return;
    int r0 = rowptr[n], r1 = rowptr[n + 1];
    for (int i = r0 + 1; i < r1; ++i) {
        int v = csr[i];
        int j = i - 1;
        while (j >= r0 && csr[j] > v) { csr[j + 1] = csr[j]; --j; }
        csr[j + 1] = v;
    }
}

// ---------------- Gather: mean of neighbor rows -> mean_out ----------------
__global__ __launch_bounds__(256) void k_gather(
    const float* __restrict__ h, const int* __restrict__ rowptr,
    const int* __restrict__ csr_src, float* __restrict__ mean_out) {
    int t = threadIdx.x;
    int lane = t & 63, wid = t >> 6;
    int n = blockIdx.x * 4 + wid;
    if (n >= NN) return;

    int r0 = rowptr[n], r1 = rowptr[n + 1];
    float s = 0.f;
    for (int base = r0; base < r1; base += 64) {
        int last = r1 - 1;
        int ii = base + lane;
        int idx = csr_src[(ii <= last) ? ii : last];  // coalesced, clamped
        int m = r1 - base;
        if (m > 64) m = 64;
        int j = 0;
        for (; j + 8 <= m; j += 8) {
            int i0 = __shfl(idx, j + 0, 64), i1 = __shfl(idx, j + 1, 64);
            int i2 = __shfl(idx, j + 2, 64), i3 = __shfl(idx, j + 3, 64);
            int i4 = __shfl(idx, j + 4, 64), i5 = __shfl(idx, j + 5, 64);
            int i6 = __shfl(idx, j + 6, 64), i7 = __shfl(idx, j + 7, 64);
            float v0 = h[i0 * D + lane], v1 = h[i1 * D + lane];
            float v2 = h[i2 * D + lane], v3 = h[i3 * D + lane];
            float v4 = h[i4 * D + lane], v5 = h[i5 * D + lane];
            float v6 = h[i6 * D + lane], v7 = h[i7 * D + lane];
            s += v0; s += v1; s += v2; s += v3;
            s += v4; s += v5; s += v6; s += v7;
        }
        for (; j + 4 <= m; j += 4) {
            int i0 = __shfl(idx, j + 0, 64), i1 = __shfl(idx, j + 1, 64);
            int i2 = __shfl(idx, j + 2, 64), i3 = __shfl(idx, j + 3, 64);
            float v0 = h[i0 * D + lane], v1 = h[i1 * D + lane];
            float v2 = h[i2 * D + lane], v3 = h[i3 * D + lane];
            s += v0; s += v1; s += v2; s += v3;
        }
        for (; j < m; ++j) {
            int i0 = __shfl(idx, j, 64);
            s += h[i0 * D + lane];
        }
    }
    float deg = (float)(r1 - r0);
    mean_out[n * D + lane] = s / fmaxf(deg, 1.0f);
}

// ---------------- Matvec: SAGE transform + skip linear ----------------
// Outer-product restructure. 8 waves/block, each wave owns 8 nodes
// (block = 64 nodes, grid covers NN exactly; NN%8==0 so active waves are
// full). Weights staged once to LDS (48 KB); per K-chunk of 16 only 48
// weight floats live in VGPRs (amortized over 8 nodes) -> ~110 VGPR, no
// AGPR shuffling (the old 192-reg weight set overflowed into AGPRs and
// capped residency at ~1.6 waves/SIMD). Activations are loaded coalesced
// into registers and broadcast with v_readlane at compile-time lane
// indices: the inner loop is pure VALU (readlane+fmac), ZERO LDS
// broadcasts, no SMEM/DS lgkmcnt mixing. The 8 epilogue norm chains are
// independent -> the shfl_xor butterflies pipeline instead of
// serializing. Per-(node,o) FMA chains keep ascending-k order with the
// exact old expressions -> hp is BIT-IDENTICAL to the previous kernel.
__global__ __launch_bounds__(512, 3) void k_matvec(
    const float* __restrict__ h, float* __restrict__ hp,
    const float* __restrict__ Wa, const float* __restrict__ ba,
    const float* __restrict__ Wr, const float* __restrict__ Wl,
    const float* __restrict__ bl) {
    __shared__ float lw[3 * D * D];   // 49152 B: [Wa | Wr | Wl], row-major [k][o]
    int t = threadIdx.x, lane = t & 63, wid = t >> 6;

    // stage weights (coalesced float4), once per block
    {
        float4* d4 = (float4*)lw;
        const float4* s4;
        s4 = (const float4*)Wa; d4[t] = s4[t]; d4[t + 512] = s4[t + 512];
        s4 = (const float4*)Wr; d4[1024 + t] = s4[t]; d4[1024 + t + 512] = s4[t + 512];
        s4 = (const float4*)Wl; d4[2048 + t] = s4[t]; d4[2048 + t + 512] = s4[t + 512];
    }
    __syncthreads();

    int wbase = (blockIdx.x * 8 + wid) * 8;   // first node of this wave's tile
    if (wbase >= NN) return;

    float bav = ba[lane], blv = bl[lane];

    // activations: 8 node rows (mean from hp, h from h) -> 16 regs/lane
    const float4* gm = (const float4*)(hp + (size_t)wbase * D);
    const float4* gh = (const float4*)(h  + (size_t)wbase * D);
    float4 vm0 = gm[lane], vm1 = gm[lane + 64];
    float4 vh0 = gh[lane], vh1 = gh[lane + 64];
    float mreg[8] = {vm0.x, vm0.y, vm0.z, vm0.w, vm1.x, vm1.y, vm1.z, vm1.w};
    float hreg[8] = {vh0.x, vh0.y, vh0.z, vh0.w, vh1.x, vh1.y, vh1.z, vh1.w};

    float am[8], rm[8], lm[8];
    #pragma unroll
    for (int i = 0; i < 8; ++i) { am[i] = 0.f; rm[i] = 0.f; lm[i] = 0.f; }

    #pragma unroll
    for (int c = 0; c < 4; ++c) {
        // chunk weights: 48 floats, lane-stride-1 LDS reads (2-way = free)
        float wa16[16], wr16[16], wl16[16];
        #pragma unroll
        for (int j = 0; j < 16; ++j) {
            wa16[j] = lw[(c * 16 + j) * D + lane];
            wr16[j] = lw[4096 + (c * 16 + j) * D + lane];
            wl16[j] = lw[8192 + (c * 16 + j) * D + lane];
        }
        #pragma unroll
        for (int i = 0; i < 8; ++i) {
            #pragma unroll
            for (int q = 0; q < 16; ++q) {
                const int kk = c * 16 + q;              // global k, ascending
                const int fid = i * 16 + (kk >> 2);     // float4 slot 0..127
                const int rsel = (fid < 64) ? (kk & 3) : 4 + (kk & 3);
                const int lsel = fid & 63;              // compile-time lane
                float mv = RLF(mreg[rsel], lsel);
                float hv = RLF(hreg[rsel], lsel);
                am[i] += mv * wa16[q];
                rm[i] += hv * wr16[q];
                lm[i] += hv * wl16[q];
            }
        }
    }

    #pragma unroll
    for (int i = 0; i < 8; ++i) {
        float sage = am[i] + bav + rm[i];
        float ss = waveSum(sage * sage);
        float inv = 1.0f / (sqrtf(ss) + 1e-12f);
        float hpv = sage * inv + lm[i] + blv;
        hp[(size_t)(wbase + i) * D + lane] = hpv;
    }
}

// BN stat partials over the finished hp buffer. Replicates the OLD
// k_matvec accumulation order exactly (same grid, same wave->node
// grid-stride, same reduce tree) -> stats are BIT-IDENTICAL to the
// previous passing kernel; zero numerical risk to the VQ argmax ids.
__global__ __launch_bounds__(256) void k_bnstats(
    const float* __restrict__ hp, float* __restrict__ partials) {
    __shared__ float red[2][4][D];
    int t = threadIdx.x, lane = t & 63, wid = t >> 6;
    int wg = blockIdx.x * 4 + wid;
    const int wstep = GRID_A * 4;
    float accS = 0.f, accQ = 0.f;
    for (int n = wg; n < NN; n += wstep) {
        float hpv = hp[(size_t)n * D + lane];
        accS += hpv;
        accQ += hpv * hpv;
    }
    red[0][wid][lane] = accS;
    red[1][wid][lane] = accQ;
    __syncthreads();
    if (wid == 0) {
        float s0 = (red[0][0][lane] + red[0][1][lane]) + (red[0][2][lane] + red[0][3][lane]);
        float q0 = (red[1][0][lane] + red[1][1][lane]) + (red[1][2][lane] + red[1][3][lane]);
        partials[blockIdx.x * 128 + lane]      = s0;
        partials[blockIdx.x * 128 + 64 + lane] = q0;
    }
}

// Parallel deterministic reduction of BN stat partials.
__global__ __launch_bounds__(256) void k_red_stats(
    const float* __restrict__ part, float* __restrict__ stats) {
    __shared__ float sm[256];
    int c = blockIdx.x;      // 0..127
    int i = threadIdx.x;     // 0..255
    float s = 0.f;
    #pragma unroll
    for (int k = 0; k < 8; ++k)
        s += part[(size_t)(i * 8 + k) * 128 + c];
    sm[i] = s;
    __syncthreads();
    #pragma unroll
    for (int off = 128; off >= 1; off >>= 1) {
        if (i < off) sm[i] += sm[i + off];
        __syncthreads();
    }
    if (i == 0) stats[c] = sm[0];
}

// ---------------- Layer part B: BN + ReLU + x_local accumulate + residual VQ
// Quad-per-node scheme (see round-0 notes): residual in registers, DPP quad
// reduces, serial first-max argmax; bit-identical sims to the wave-per-node
// original.
#define CBSTRIDE 68
__global__ __launch_bounds__(256) void k_layer_b(
    float* __restrict__ hp,              // in: pre-BN h'; out: post-ReLU h
    const float* __restrict__ stats,
    const float* __restrict__ gamma, const float* __restrict__ beta,
    const float* __restrict__ cbs,       // [RVQ][CODES][D] for this layer
    float* __restrict__ x_local,
    float* __restrict__ ids_out,         // [NN][L*RVQ] region base
    int layer, float* __restrict__ commit, int first_layer) {
    __shared__ alignas(16) float scb[RVQ * CODES * CBSTRIDE];
    __shared__ alignas(16) float sscale[D];
    __shared__ alignas(16) float sshift[D];
    __shared__ float sred[4];
    int t = threadIdx.x, lane = t & 63, wid = t >> 6;

    // normalize codebook rows into LDS (identical math to before)
    for (int row = wid; row < RVQ * CODES; row += 4) {
        float v = cbs[row * D + lane];
        float ss = waveSum(v * v);
        scb[row * CBSTRIDE + lane] = v / (sqrtf(ss) + 1e-12f);
    }
    // BN scale/shift per channel
    if (t < D) {
        float mu = stats[t] * (1.0f / NN);
        float var = stats[64 + t] * (1.0f / NN) - mu * mu;
        float scale = rsqrtf(var + BN_EPS) * gamma[t];
        sscale[t] = scale;
        sshift[t] = beta[t] - mu * scale;
    }
    __syncthreads();

    int gid = blockIdx.x * 256 + t;
    int node = gid >> 2;      // one node per quad of lanes
    int part = t & 3;         // which 16-channel slice this lane owns
    float closs = 0.f;

    if (node < NN) {
        float res[16];
        size_t base = (size_t)node * D + part * 16;
        const float4* hr = (const float4*)(hp + base);
        float4* hw = (float4*)(hp + base);
        float4* xw = (float4*)(x_local + base);
        const float4* scp = (const float4*)(sscale + part * 16);
        const float4* shp = (const float4*)(sshift + part * 16);

        #pragma unroll
        for (int i = 0; i < 4; ++i) {
            float4 v = hr[i];
            float4 sc = scp[i], sh = shp[i];
            float4 hn;
            hn.x = fmaxf(v.x * sc.x + sh.x, 0.f);
            hn.y = fmaxf(v.y * sc.y + sh.y, 0.f);
            hn.z = fmaxf(v.z * sc.z + sh.z, 0.f);
            hn.w = fmaxf(v.w * sc.w + sh.w, 0.f);
            hw[i] = hn;
            if (first_layer) {
                xw[i] = hn;
            } else {
                float4 xl = xw[i];
                xl.x += hn.x; xl.y += hn.y; xl.z += hn.z; xl.w += hn.w;
                xw[i] = xl;
            }
            res[4 * i + 0] = hn.x; res[4 * i + 1] = hn.y;
            res[4 * i + 2] = hn.z; res[4 * i + 3] = hn.w;
        }

        int bis[RVQ];
        #pragma unroll
        for (int r = 0; r < RVQ; ++r) {
            float sims[CODES];
            #pragma unroll
            for (int j = 0; j < CODES; ++j) {
                const float* cr = &scb[(r * CODES + j) * CBSTRIDE + part * 16];
                float4 c0 = *(const float4*)(cr + 0);
                float4 c1 = *(const float4*)(cr + 4);
                float4 c2 = *(const float4*)(cr + 8);
                float4 c3 = *(const float4*)(cr + 12);
                float a = res[0] * c0.x;
                a += res[1] * c0.y;  a += res[2] * c0.z;  a += res[3] * c0.w;
                a += res[4] * c1.x;  a += res[5] * c1.y;  a += res[6] * c1.z;  a += res[7] * c1.w;
                a += res[8] * c2.x;  a += res[9] * c2.y;  a += res[10] * c2.z; a += res[11] * c2.w;
                a += res[12] * c3.x; a += res[13] * c3.y; a += res[14] * c3.z; a += res[15] * c3.w;
                float b = a + qxor1(a);
                sims[j] = b + qxor2(b);
            }
            float bv = sims[0];
            int bi = 0;
            #pragma unroll
            for (int j = 1; j < CODES; ++j)
                if (sims[j] > bv) { bv = sims[j]; bi = j; }

            const float* qr = &scb[(r * CODES + bi) * CBSTRIDE + part * 16];
            #pragma unroll
            for (int i = 0; i < 4; ++i) {
                float4 q = *(const float4*)(qr + 4 * i);
                float d0 = q.x - res[4 * i + 0]; closs += d0 * d0; res[4 * i + 0] = -d0;
                float d1 = q.y - res[4 * i + 1]; closs += d1 * d1; res[4 * i + 1] = -d1;
                float d2 = q.z - res[4 * i + 2]; closs += d2 * d2; res[4 * i + 2] = -d2;
                float d3 = q.w - res[4 * i + 3]; closs += d3 * d3; res[4 * i + 3] = -d3;
            }
            bis[r] = bi;
        }
        if (part == 0) {
            ids_out[(size_t)node * (L * RVQ) + layer * RVQ + 0] = (float)bis[0];
            ids_out[(size_t)node * (L * RVQ) + layer * RVQ + 1] = (float)bis[1];
            ids_out[(size_t)node * (L * RVQ) + layer * RVQ + 2] = (float)bis[2];
        }
    }

    closs = waveSum(closs);
    if (lane == 0) sred[wid] = closs;
    __syncthreads();
    if (t == 0) {
        float tot = (sred[0] + sred[1]) + (sred[2] + sred[3]);
        atomicAdd(commit, tot * (COMMIT_W / (float)(NN * D)));
    }
}

// ---------------- Heads ----------------
__global__ __launch_bounds__(256, 2) void k_head(
    const float* __restrict__ x_local,
    const float* __restrict__ Wp, const float* __restrict__ bp,
    const float* __restrict__ Wg, const float* __restrict__ bg,
    float* __restrict__ pred, float* __restrict__ gnn) {
    int t = threadIdx.x, lane = t & 63, wid = t >> 6;
    int jsafe = (lane < 9) ? lane : 0;

    float wp[D], wg[D];
    #pragma unroll
    for (int k = 0; k < D; ++k) {
        wp[k] = Wp[k * D + lane];
        wg[k] = Wg[k * 9 + jsafe];
    }
    float bpv = bp[lane], bgv = bg[jsafe];

    int w = blockIdx.x * 4 + wid;
    int wstep = gridDim.x * 4;
    for (int n = w; n < NN; n += wstep) {
        int nu = __builtin_amdgcn_readfirstlane(n);
        const float4* xrow = (const float4*)(x_local + (size_t)nu * D);
        float p = 0.f, g = 0.f;
        #pragma unroll
        for (int j = 0; j < 16; ++j) {
            float4 x4 = xrow[j];
            p += x4.x * wp[4 * j + 0]; g += x4.x * wg[4 * j + 0];
            p += x4.y * wp[4 * j + 1]; g += x4.y * wg[4 * j + 1];
            p += x4.z * wp[4 * j + 2]; g += x4.z * wg[4 * j + 2];
            p += x4.w * wp[4 * j + 3]; g += x4.w * wg[4 * j + 3];
        }
        pred[(size_t)n * D + lane] = p + bpv;
        if (lane < 9) gnn[(size_t)n * 9 + lane] = g + bgv;
    }
}

extern "C" void kernel_launch(void* const* d_in, const int* in_sizes, int n_in,
                              void* d_out, int out_size, void* d_ws, size_t ws_size,
                              hipStream_t stream) {
    const float* x   = (const float*)d_in[0];
    const int* ei    = (const int*)d_in[1];
    const float* Wa  = (const float*)d_in[2];
    const float* ba  = (const float*)d_in[3];
    const float* Wr  = (const float*)d_in[4];
    const float* Wl  = (const float*)d_in[5];
    const float* bl  = (const float*)d_in[6];
    const float* gamma = (const float*)d_in[7];
    const float* beta  = (const float*)d_in[8];
    const float* cbs = (const float*)d_in[9];
    const float* Wp  = (const float*)d_in[10];
    const float* bp  = (const float*)d_in[11];
    const float* Wg  = (const float*)d_in[12];
    const float* bg  = (const float*)d_in[13];

    const int* src = ei;
    const int* dst = ei + NE;

    int*   ws_i  = (int*)d_ws;
    float* ws_f  = (float*)d_ws;
    int* rowptr  = ws_i + OFS_ROWPTR;
    int* cnt     = ws_i + OFS_CNT;
    int* cursor  = ws_i + OFS_CURSOR;
    int* bsums   = ws_i + OFS_BSUMS;
    int* boffs   = ws_i + OFS_BOFFS;
    float* stats = ws_f + OFS_STATS;
    int* csr_src = ws_i + OFS_CSR;
    float* hA    = ws_f + OFS_HA;
    float* hB    = ws_f + OFS_HB;
    float* xloc  = ws_f + OFS_XLOC;
    float* part  = ws_f + OFS_PART;

    float* out    = (float*)d_out;
    float* pred   = out + OUT_PRED;
    float* commit = out + OUT_COMMIT;
    float* ids    = out + OUT_IDS;
    float* gnn    = out + OUT_GNN;

    hipMemsetAsync(cnt, 0, NN * sizeof(int), stream);
    hipMemsetAsync(commit, 0, sizeof(float), stream);

    // CSR build
    k_count<<<(NE + 255) / 256, 256, 0, stream>>>(dst, cnt);
    int nscan = (NN + SCAN_B - 1) / SCAN_B;  // 98
    k_scan1<<<nscan, SCAN_B, 0, stream>>>(cnt, rowptr, bsums);
    k_scan2<<<1, SCAN_B, 0, stream>>>(bsums, boffs, nscan);
    k_scan3<<<nscan, SCAN_B, 0, stream>>>(rowptr, boffs);
    k_cursor<<<(NN + 1023) / 1024, 1024, 0, stream>>>(rowptr, cursor);
    k_fill<<<(NE + 255) / 256, 256, 0, stream>>>(src, dst, cursor, csr_src);
    k_sortrows<<<(NN + 255) / 256, 256, 0, stream>>>(rowptr, csr_src);

    // layers
    const float* hin = x;
    float* bufs[2] = {hA, hB};
    const int nblk_mv = (NN + 63) / 64;       // 1563 blocks, 64 nodes/block
    const int nblk_b  = (NN * 4 + 255) / 256; // 1563 blocks, one node per quad
    for (int i = 0; i < L; ++i) {
        float* hp = bufs[i & 1];
        k_gather<<<(NN + 3) / 4, 256, 0, stream>>>(hin, rowptr, csr_src, hp);
        k_matvec<<<nblk_mv, 512, 0, stream>>>(hin, hp,
                                              Wa + i * D * D, ba + i * D,
                                              Wr + i * D * D, Wl + i * D * D, bl + i * D);
        k_bnstats<<<GRID_A, 256, 0, stream>>>(hp, part);
        k_red_stats<<<128, 256, 0, stream>>>(part, stats + i * 128);
        k_layer_b<<<nblk_b, 256, 0, stream>>>(hp, stats + i * 128,
                                              gamma + i * D, beta + i * D,
                                              cbs + i * RVQ * CODES * D,
                                              xloc, ids, i, commit, (i == 0) ? 1 : 0);
        hin = hp;
    }

    // heads
    k_head<<<2048, 256, 0, stream>>>(xloc, Wp, bp, Wg, bg, pred, gnn);
}